// Round 3
// baseline (514.752 us; speedup 1.0000x reference)
//
#include <hip/hip_runtime.h>
#include <hip/hip_cooperative_groups.h>
#include <hip/hip_bf16.h>
#include <math.h>

namespace cg = cooperative_groups;

#define T_SEQ 4096
#define NBATCH 4
#define C_EMB 512
#define HEAD 64
#define CHUNK 8                  // k-tiles (of 64) per attn job
#define EPB 144                  // per batch: sum over Q of ceil((2Q+2)/8), Q=0..31

typedef __attribute__((ext_vector_type(8))) short short8;
typedef __attribute__((ext_vector_type(4))) short short4v;
typedef __attribute__((ext_vector_type(4))) float f32x4;

// scale folded into q at projection: exp(s/sqrt(512)) = exp2(qhat . k)
#define C2 (0.044194173824159216f * 1.44269504088896340736f)

__device__ __forceinline__ unsigned short f2bf(float f) {
    union { float f; unsigned u; } v; v.f = f;
    unsigned u = v.u;
    u += 0x7FFF + ((u >> 16) & 1);   // round-to-nearest-even
    return (unsigned short)(u >> 16);
}
// packed f32x2 -> bf16x2 (v_cvt_pk_bf16_f32); low 16 = a, high 16 = b
__device__ __forceinline__ unsigned pk2bf(float a, float b) {
    __hip_bfloat162 h = __float22bfloat162_rn(make_float2(a, b));
    return *(unsigned*)&h;
}
__device__ __forceinline__ float bf2f(unsigned short u) {
    union { unsigned u; float f; } v; v.u = ((unsigned)u) << 16;
    return v.f;
}

// async global->LDS, 16 B per lane; LDS dest = wave-uniform base + lane*16
#define GLD_LDS16(gp, lp)                                                     \
    __builtin_amdgcn_global_load_lds(                                         \
        (const __attribute__((address_space(1))) void*)(gp),                  \
        (__attribute__((address_space(3))) void*)(lp), 16, 0, 0)

// ---------------- shared-memory layouts (union: phases are sequential) -------
struct ProjSm {
    unsigned short Wl[2][12288];     // 49152 B, per-chunk W image
    unsigned short Xl[2][32][72];    //  9216 B (epilogue reuses as Vsh[64][40])
};
struct AttnSm {
    unsigned short Ks[2][64][72];    // [buf][kpos][h]
    unsigned short Vs[2][64][72];    // [buf][h][phi(kpos)]
};
union MegaSm {                        // 58368 B -> 2 blocks/CU
    ProjSm p;
    AttnSm a;
};

// ---------------- Phase 0: W conversion, per-chunk LDS image -----------------
// wt2 short index: (((c*12 + tile)*2 + kc)*64 + lane)*8 + i  holds
// bf16(W_w[k][n]), w=tile>>2, n=(tile&3)*16+(lane&15), k=c*64+kc*32+(lane>>4)*8+i.
__device__ __forceinline__ void phase_wcvt(
    int gid, const float* __restrict__ Wq, const float* __restrict__ Wk,
    const float* __restrict__ Wv, unsigned short* __restrict__ wt2)
{
    if (gid >= 12288) return;
    const int lane = gid & 63;
    int rest = gid >> 6;
    const int kc   = rest & 1; rest >>= 1;
    const int tile = rest % 12;
    const int c    = rest / 12;
    const float* W = (tile < 4) ? Wq : (tile < 8) ? Wk : Wv;
    const int n  = (tile & 3) * 16 + (lane & 15);
    const int k0 = c * 64 + kc * 32 + (lane >> 4) * 8;
    unsigned short tmp[8];
#pragma unroll
    for (int i = 0; i < 8; ++i) tmp[i] = f2bf(W[(size_t)(k0 + i) * HEAD + n]);
    *(short8*)(wt2 + (size_t)gid * 8) = *(short8*)tmp;
}

// ---------------- Phase 1: projection (32 x-rows/block, 8 waves) -------------
__device__ __forceinline__ void phase_proj(
    ProjSm* sm, int bid, int tid,
    const float* __restrict__ x, const unsigned short* __restrict__ wt2,
    unsigned short* __restrict__ qout, unsigned short* __restrict__ kout,
    unsigned short* __restrict__ vt)
{
    const int wave = tid >> 6;
    const int lane = tid & 63;
    const int l16  = lane & 15;
    const int quad = lane >> 4;
    const int row0 = bid * 32;
    const int mq   = wave & 1;           // M-quarter (16 rows)
    const int ng   = wave >> 1;          // N-group: tiles ng*3 .. ng*3+2

    const bool xst = tid < 256;
    const int xrow = tid >> 3;
    const int xc8  = (tid & 7) * 8;

    f32x4 acc[3];
#pragma unroll
    for (int j = 0; j < 3; ++j) acc[j] = (f32x4){0.f, 0.f, 0.f, 0.f};

    // ---- stage chunk 0 into buffer 0 ----
#pragma unroll
    for (int m = 0; m < 3; ++m)
        GLD_LDS16(wt2 + (size_t)(m * 4096 + wave * 512 + lane * 8),
                  &sm->Wl[0][m * 4096 + wave * 512]);
    if (xst) {
        const float* xs = x + (size_t)(row0 + xrow) * C_EMB + xc8;
        float4 a = *(const float4*)(xs);
        float4 b = *(const float4*)(xs + 4);
        int4 ai = make_int4((int)pk2bf(a.x, a.y), (int)pk2bf(a.z, a.w),
                            (int)pk2bf(b.x, b.y), (int)pk2bf(b.z, b.w));
        *(short8*)&sm->Xl[0][xrow][xc8] = *(short8*)&ai;
    }
    __syncthreads();

    for (int c = 0; c < 8; ++c) {
        const int bb = c & 1;
        if (c < 7) {                     // stage chunk c+1 into other buffer
            const int nb = bb ^ 1;
            const size_t g0 = (size_t)(c + 1) * 12288;
#pragma unroll
            for (int m = 0; m < 3; ++m)
                GLD_LDS16(wt2 + g0 + (size_t)(m * 4096 + wave * 512 + lane * 8),
                          &sm->Wl[nb][m * 4096 + wave * 512]);
            if (xst) {
                const float* xs = x + (size_t)(row0 + xrow) * C_EMB + (c + 1) * 64 + xc8;
                float4 a = *(const float4*)(xs);
                float4 b = *(const float4*)(xs + 4);
                int4 ai = make_int4((int)pk2bf(a.x, a.y), (int)pk2bf(a.z, a.w),
                                    (int)pk2bf(b.x, b.y), (int)pk2bf(b.z, b.w));
                *(short8*)&sm->Xl[nb][xrow][xc8] = *(short8*)&ai;
            }
        }

        // compute on buffer bb: 2 kc x (1 A-frag, 3 B-frags, 3 MFMA)
#pragma unroll
        for (int kc = 0; kc < 2; ++kc) {
            short8 a0 = *(const short8*)&sm->Xl[bb][mq * 16 + l16][kc * 32 + quad * 8];
#pragma unroll
            for (int j = 0; j < 3; ++j) {
                const int ct = ng * 3 + j;
                short8 bfr = *(const short8*)&sm->Wl[bb][(ct * 128 + kc * 64 + lane) * 8];
                acc[j] = __builtin_amdgcn_mfma_f32_16x16x32_bf16(a0, bfr, acc[j], 0, 0, 0);
            }
        }
        __syncthreads();
    }

    // epilogue: wave owns (mq, tiles ng*3..ng*3+2); tile ct: m=ct>>2, n=ct&3
    unsigned short (*Vsh)[40] = (unsigned short (*)[40]) & sm->Xl[0][0][0];
#pragma unroll
    for (int j = 0; j < 3; ++j) {
        const int ct = ng * 3 + j;
        const int m  = ct >> 2;
        const int n  = ct & 3;
#pragma unroll
        for (int r = 0; r < 4; ++r) {
            const int row = row0 + mq * 16 + quad * 4 + r;
            if (m == 0)
                qout[(size_t)row * HEAD + n * 16 + l16] = f2bf(acc[j][r] * C2);
            else if (m == 1)
                kout[(size_t)row * HEAD + n * 16 + l16] = f2bf(acc[j][r]);
            else
                Vsh[n * 16 + l16][mq * 16 + quad * 4 + r] = f2bf(acc[j][r]);
        }
    }
    __syncthreads();
    if (tid < 256) {
        int h  = tid >> 2;
        int tc = (tid & 3) * 8;
        int b  = row0 >> 12;
        int t0 = row0 & (T_SEQ - 1);
        unsigned short* dst = vt + ((size_t)(b * HEAD + h)) * T_SEQ + t0 + tc;
        *(short8*)dst = *(const short8*)&Vsh[h][tc];
    }
}

// stage one V row-chunk (8 cols from vc, vc multiple of 8) phi-swizzled:
// col c bits [s|d|q1 q0|r1 r0] -> position [s|q1 q0|d|r1 r0]
__device__ __forceinline__ void stage_v8(unsigned short (*Vbuf)[72], int sr, int pos0,
                                         short8 v0) {
    *(short4v*)&Vbuf[sr][pos0]     = __builtin_shufflevector(v0, v0, 0, 1, 2, 3);
    *(short4v*)&Vbuf[sr][pos0 + 8] = __builtin_shufflevector(v0, v0, 4, 5, 6, 7);
}

// ---------------- Phase 2: attention job (128 q-rows, <=8 k-tiles) -----------
// S^T trick (lane holds S[q=l16][64 k-cols]); K/V LDS shared by 8 waves.
__device__ void phase_attn_job(
    AttnSm* sm, int tid, int b, int Q, int c,
    const unsigned short* __restrict__ qb, const unsigned short* __restrict__ kb,
    const unsigned short* __restrict__ vt, unsigned short* __restrict__ po,
    float* __restrict__ pl)
{
    const int wave = tid >> 6;            // 0..7
    const int lane = tid & 63;
    const int l16  = lane & 15;
    const int quad = lane >> 4;

    const size_t base = (size_t)b * T_SEQ;
    const int qrow0 = Q * 128 + wave * 16;      // wave's first q-row
    const int qrow  = qrow0 + l16;
    short8 aq0 = *(const short8*)(qb + (base + qrow) * HEAD + quad * 8);
    short8 aq1 = *(const short8*)(qb + (base + qrow) * HEAD + 32 + quad * 8);

    float lacc = 0.f;
    f32x4 o[4];
#pragma unroll
    for (int n = 0; n < 4; ++n) o[n] = (f32x4){0.f, 0.f, 0.f, 0.f};

    const int nk  = 2 * Q + 2;                  // causal k-tiles for this q-tile
    const int kt0 = c * CHUNK;
    const int np  = min(CHUNK, nk - kt0);       // 2..8 64-wide iterations

    // staging role: 512 threads, each 16 B of K and 16 B of V per tile
    const int sr   = tid >> 3;            // 0..63 (K k-row / V h-row)
    const int scK  = (tid & 7) * 8;       // K col (h) 0..56
    const int vc   = scK;                 // V col (kpos chunk)
    const int pos0 = (vc & 32) + ((vc & 8) << 1) + ((vc & 16) >> 2);

    short8 kra, vra;
    {
        const int kbase = kt0 * 64;
        kra = *(const short8*)(kb + (base + kbase + sr) * HEAD + scK);
        vra = *(const short8*)(vt + ((size_t)(b * HEAD + sr)) * T_SEQ + kbase + vc);
    }
    __syncthreads();                      // prior users of these LDS bufs done
    *(short8*)&sm->Ks[0][sr][scK] = kra;
    stage_v8(sm->Vs[0], sr, pos0, vra);

    for (int p = 0; p < np; ++p) {
        const int cur = p & 1;
        const int kbase = (kt0 + p) * 64;
        __syncthreads();                 // LDS[cur] ready; prev-iter reads done

        if (p + 1 < np) {                // prefetch next tile into regs
            const int nb = kbase + 64;
            kra = *(const short8*)(kb + (base + nb + sr) * HEAD + scK);
            vra = *(const short8*)(vt + ((size_t)(b * HEAD + sr)) * T_SEQ + nb + vc);
        }

        // wave-level early-out: whole tile beyond this wave's causal range
        const bool live = (kbase <= qrow0 + 15);
        if (live) {
            // S^T = K.Q^T: lane gets S[q=l16][c = kbase + n*16 + quad*4 + r]
            f32x4 s[4];
            __builtin_amdgcn_s_setprio(1);   // T5: favor MFMA waves
#pragma unroll
            for (int n = 0; n < 4; ++n) {
                short8 bk0 = *(const short8*)&sm->Ks[cur][n * 16 + l16][quad * 8];
                short8 bk1 = *(const short8*)&sm->Ks[cur][n * 16 + l16][32 + quad * 8];
                f32x4 accS = (f32x4){0.f, 0.f, 0.f, 0.f};
                accS = __builtin_amdgcn_mfma_f32_16x16x32_bf16(bk0, aq0, accS, 0, 0, 0);
                accS = __builtin_amdgcn_mfma_f32_16x16x32_bf16(bk1, aq1, accS, 0, 0, 0);
                s[n] = accS;
            }
            __builtin_amdgcn_s_setprio(0);

            // P = exp2(S); zero masked cols on diagonal tiles
#pragma unroll
            for (int n = 0; n < 4; ++n)
#pragma unroll
                for (int r = 0; r < 4; ++r)
                    s[n][r] = __builtin_amdgcn_exp2f(s[n][r]);

            if (kbase + 63 > qrow0) {
                const int cb = kbase + quad * 4;
#pragma unroll
                for (int n = 0; n < 4; ++n)
#pragma unroll
                    for (int r = 0; r < 4; ++r)
                        if (cb + n * 16 + r > qrow) s[n][r] = 0.f;
            }

#pragma unroll
            for (int n = 0; n < 4; ++n)
                lacc += (s[n][0] + s[n][1]) + (s[n][2] + s[n][3]);

            // PV: pack A-frag locally (k-order matches phi-swizzled V), B = b128
#pragma unroll
            for (int st = 0; st < 2; ++st) {
                int4 ai = make_int4(
                    (int)pk2bf(s[2 * st][0],     s[2 * st][1]),
                    (int)pk2bf(s[2 * st][2],     s[2 * st][3]),
                    (int)pk2bf(s[2 * st + 1][0], s[2 * st + 1][1]),
                    (int)pk2bf(s[2 * st + 1][2], s[2 * st + 1][3]));
                short8 af = *(short8*)&ai;
                __builtin_amdgcn_s_setprio(1);
#pragma unroll
                for (int n = 0; n < 4; ++n) {
                    short8 bv = *(const short8*)&sm->Vs[cur][n * 16 + l16][32 * st + quad * 8];
                    o[n] = __builtin_amdgcn_mfma_f32_16x16x32_bf16(af, bv, o[n], 0, 0, 0);
                }
                __builtin_amdgcn_s_setprio(0);
            }
        }

        if (p + 1 < np) {                // stage next tile into the other buffer
            const int nxt = cur ^ 1;
            *(short8*)&sm->Ks[nxt][sr][scK] = kra;
            stage_v8(sm->Vs[nxt], sr, pos0, vra);
        }
    }

    // reduce l over the quad dimension (q-row = l16 per lane)
    lacc += __shfl_xor(lacc, 16);
    lacc += __shfl_xor(lacc, 32);

    // pid = canonical (b, e(Q,c)) index; e = 2g(g+1) + t(g+1) + c, g=Q>>2, t=Q&3
    const int g2 = Q >> 2, t2 = Q & 3;
    const int pid = b * EPB + 2 * g2 * (g2 + 1) + t2 * (g2 + 1) + c;
#pragma unroll
    for (int n = 0; n < 4; ++n)
#pragma unroll
        for (int r = 0; r < 4; ++r) {
            int lr = wave * 16 + quad * 4 + r;          // 0..127
            po[(size_t)pid * 8192 + lr * 64 + n * 16 + l16] = f2bf(o[n][r]);
        }
    if (quad == 0)
        pl[pid * 128 + wave * 16 + l16] = lacc;
}

// block -> attn job(s): per batch, 128 long jobs (120 np=8, 8 np=6) map 1:1
// to 128 blocks; the 16 short jobs (8 np=4, 8 np=2) are second jobs for
// blocks m in [112,128). Max per-block work = 10 k-tile iterations.
__device__ __forceinline__ void run_attn_jobs(
    AttnSm* sm, int bid, int tid,
    const unsigned short* __restrict__ qb, const unsigned short* __restrict__ kb,
    const unsigned short* __restrict__ vt, unsigned short* __restrict__ po,
    float* __restrict__ pl)
{
    const int b = bid >> 7;              // 128 main jobs per batch
    const int m = bid & 127;
    int Q, c;
    if (m < 120) {                       // np=8 job: (Q,c) with c < (Q+1)/4
        int mm = m, q;
        for (q = 0; q < 32; ++q) { int cnt = (q + 1) >> 2; if (mm < cnt) break; mm -= cnt; }
        Q = q; c = mm;
    } else {                             // np=6 job: Q=4g+2, c=g
        int g = m - 120; Q = 4 * g + 2; c = g;
    }
    phase_attn_job(sm, tid, b, Q, c, qb, kb, vt, po, pl);
    if (m >= 112) {                      // second (short) job
        int i = m - 112;                 // 0..15
        int g = i & 7, t = i >> 3;       // t=0 -> np=2, t=1 -> np=4
        phase_attn_job(sm, tid, b, 4 * g + t, g, qb, kb, vt, po, pl);
    }
}

// ---------------- Phase 3: combine (sum <=8 bf16 partials, normalize) --------
__device__ __forceinline__ void phase_combine(
    int bid, int tid, const unsigned short* __restrict__ po,
    const float* __restrict__ pl, float* __restrict__ out)
{
    if (tid >= 256) return;
    const int gth = bid * 256 + tid;     // octet index, 131072 total
    const int h8  = gth & 7;
    const int row = gth >> 3;
    const int lr  = row & 127;
    const int Q   = (row >> 7) & 31;
    const int b   = row >> 12;
    const int g   = Q >> 2;
    const int rem = Q & 3;
    const int nc  = g + 1;
    const int e0  = 2 * g * (g + 1) + rem * (g + 1);
    const int pid0 = b * EPB + e0;       // chunk cc lives at pid0+cc

    float l = 0.f;
    float acc[8];
#pragma unroll
    for (int i = 0; i < 8; ++i) acc[i] = 0.f;
    for (int cc = 0; cc < nc; ++cc) {
        l += pl[(pid0 + cc) * 128 + lr];
        short8 p8 = *(const short8*)(po + (size_t)(pid0 + cc) * 8192 + lr * 64 + h8 * 8);
#pragma unroll
        for (int i = 0; i < 8; ++i) acc[i] += bf2f((unsigned short)p8[i]);
    }
    float inv = 1.f / l;
    float4 r0 = make_float4(acc[0] * inv, acc[1] * inv, acc[2] * inv, acc[3] * inv);
    float4 r1 = make_float4(acc[4] * inv, acc[5] * inv, acc[6] * inv, acc[7] * inv);
    float* dst = out + (size_t)gth * 8;
    *(float4*)dst       = r0;
    *(float4*)(dst + 4) = r1;
}

// ---------------- Mega-kernel: all 4 phases, grid-wide sync between ----------
__global__ __launch_bounds__(512, 4) void mega_kernel(
    const float* __restrict__ x, const float* __restrict__ Wq,
    const float* __restrict__ Wk, const float* __restrict__ Wv,
    unsigned short* __restrict__ wt2, unsigned short* __restrict__ qb,
    unsigned short* __restrict__ kb, unsigned short* __restrict__ vt,
    unsigned short* __restrict__ po, float* __restrict__ pl,
    float* __restrict__ out)
{
    __shared__ MegaSm sm;
    cg::grid_group grid = cg::this_grid();
    const int bid = blockIdx.x, tid = threadIdx.x;

    phase_wcvt(bid * 512 + tid, Wq, Wk, Wv, wt2);
    __threadfence();
    grid.sync();

    phase_proj(&sm.p, bid, tid, x, wt2, qb, kb, vt);
    __threadfence();
    grid.sync();

    run_attn_jobs(&sm.a, bid, tid, qb, kb, vt, po, pl);
    __threadfence();
    grid.sync();

    phase_combine(bid, tid, po, pl, out);
}

// ---------------- Fallback: same phases as 4 separate kernels ----------------
__global__ __launch_bounds__(512) void wcvt_k(
    const float* __restrict__ Wq, const float* __restrict__ Wk,
    const float* __restrict__ Wv, unsigned short* __restrict__ wt2) {
    phase_wcvt(blockIdx.x * 512 + threadIdx.x, Wq, Wk, Wv, wt2);
}
__global__ __launch_bounds__(512, 4) void proj_k(
    const float* __restrict__ x, const unsigned short* __restrict__ wt2,
    unsigned short* __restrict__ qb, unsigned short* __restrict__ kb,
    unsigned short* __restrict__ vt) {
    __shared__ ProjSm s;
    phase_proj(&s, blockIdx.x, threadIdx.x, x, wt2, qb, kb, vt);
}
__global__ __launch_bounds__(512, 4) void attn_k(
    const unsigned short* __restrict__ qb, const unsigned short* __restrict__ kb,
    const unsigned short* __restrict__ vt, unsigned short* __restrict__ po,
    float* __restrict__ pl) {
    __shared__ AttnSm s;
    run_attn_jobs(&s, blockIdx.x, threadIdx.x, qb, kb, vt, po, pl);
}
__global__ __launch_bounds__(256) void comb_k(
    const unsigned short* __restrict__ po, const float* __restrict__ pl,
    float* __restrict__ out) {
    phase_combine(blockIdx.x, threadIdx.x, po, pl, out);
}

extern "C" void kernel_launch(void* const* d_in, const int* in_sizes, int n_in,
                              void* d_out, int out_size, void* d_ws, size_t ws_size,
                              hipStream_t stream) {
    const float* x  = (const float*)d_in[0];
    const float* Wq = (const float*)d_in[1];
    const float* Wk = (const float*)d_in[2];
    const float* Wv = (const float*)d_in[3];
    float* out = (float*)d_out;

    char* ws = (char*)d_ws;
    unsigned short* qb = (unsigned short*)(ws);                 // 2 MB
    unsigned short* kb = (unsigned short*)(ws + (2u << 20));    // 2 MB
    unsigned short* vt = (unsigned short*)(ws + (4u << 20));    // 2 MB
    unsigned short* wt2 = (unsigned short*)(ws + (6u << 20));   // 192 KB
    float* pl = (float*)(ws + (6u << 20) + 196608);             // 294912 B
    unsigned short* po = (unsigned short*)(ws + (6u << 20) + 196608 + 294912); // 9.4 MB

    void* kargs[] = { (void*)&x, (void*)&Wq, (void*)&Wk, (void*)&Wv,
                      (void*)&wt2, (void*)&qb, (void*)&kb, (void*)&vt,
                      (void*)&po, (void*)&pl, (void*)&out };
    hipError_t err = hipLaunchCooperativeKernel(
        (void*)mega_kernel, dim3(512), dim3(512), kargs, 0, stream);
    if (err != hipSuccess) {             // fallback: 4 separate launches
        (void)hipGetLastError();
        wcvt_k<<<dim3(24), dim3(512), 0, stream>>>(Wq, Wk, Wv, wt2);
        proj_k<<<dim3(512), dim3(512), 0, stream>>>(x, wt2, qb, kb, vt);
        attn_k<<<dim3(512), dim3(512), 0, stream>>>(qb, kb, vt, po, pl);
        comb_k<<<dim3(512), dim3(256), 0, stream>>>(po, pl, out);
    }
}

// Round 4
// 116.202 us; speedup vs baseline: 4.4298x; 4.4298x over previous
//
#include <hip/hip_runtime.h>
#include <hip/hip_bf16.h>
#include <math.h>

#define T_SEQ 4096
#define NBATCH 4
#define C_EMB 512
#define HEAD 64
#define CHUNK 8                  // k-tiles (of 64) per attn job
#define EPB 144                  // per batch: sum over Q of ceil((2Q+2)/8), Q=0..31

typedef __attribute__((ext_vector_type(8))) short short8;
typedef __attribute__((ext_vector_type(4))) short short4v;
typedef __attribute__((ext_vector_type(4))) float f32x4;

// scale folded into q at projection: exp(s/sqrt(512)) = exp2(qhat . k)
#define C2 (0.044194173824159216f * 1.44269504088896340736f)

__device__ __forceinline__ unsigned short f2bf(float f) {
    union { float f; unsigned u; } v; v.f = f;
    unsigned u = v.u;
    u += 0x7FFF + ((u >> 16) & 1);   // round-to-nearest-even
    return (unsigned short)(u >> 16);
}
// packed f32x2 -> bf16x2 (v_cvt_pk_bf16_f32); low 16 = a, high 16 = b
__device__ __forceinline__ unsigned pk2bf(float a, float b) {
    __hip_bfloat162 h = __float22bfloat162_rn(make_float2(a, b));
    return *(unsigned*)&h;
}
__device__ __forceinline__ float bf2f(unsigned short u) {
    union { unsigned u; float f; } v; v.u = ((unsigned)u) << 16;
    return v.f;
}

// async global->LDS, 16 B per lane; LDS dest = wave-uniform base + lane*16
#define GLD_LDS16(gp, lp)                                                     \
    __builtin_amdgcn_global_load_lds(                                         \
        (const __attribute__((address_space(1))) void*)(gp),                  \
        (__attribute__((address_space(3))) void*)(lp), 16, 0, 0)

// ---------------- W conversion: emit the per-chunk LDS image ------------------
// wt2 short index: (((c*12 + tile)*2 + kc)*64 + lane)*8 + i  holds
// bf16(W_w[k][n]), w=tile>>2, n=(tile&3)*16+(lane&15), k=c*64+kc*32+(lane>>4)*8+i.
// Lane's 16 B IS its MFMA B-fragment -> staged LDS reads are conflict-free.
__global__ __launch_bounds__(64) void wcvt_kernel(
    const float* __restrict__ Wq, const float* __restrict__ Wk,
    const float* __restrict__ Wv, unsigned short* __restrict__ wt2)
{
    const int gid  = blockIdx.x * 64 + threadIdx.x;   // 0..12287
    const int lane = gid & 63;
    int rest = gid >> 6;
    const int kc   = rest & 1; rest >>= 1;
    const int tile = rest % 12;
    const int c    = rest / 12;
    const float* W = (tile < 4) ? Wq : (tile < 8) ? Wk : Wv;
    const int n  = (tile & 3) * 16 + (lane & 15);
    const int k0 = c * 64 + kc * 32 + (lane >> 4) * 8;
    unsigned short tmp[8];
#pragma unroll
    for (int i = 0; i < 8; ++i) tmp[i] = f2bf(W[(size_t)(k0 + i) * HEAD + n]);
    *(short8*)(wt2 + (size_t)gid * 8) = *(short8*)tmp;
}

// ---------------- Projection v5: global_load_lds W staging --------------------
__global__ __launch_bounds__(512, 4) void proj_kernel(
    const float* __restrict__ x,            // [16384, 512]
    const unsigned short* __restrict__ wt2, // [8][12][2][64][8] bf16
    unsigned short* __restrict__ qout,      // [16384, 64]  (pre-scaled by C2)
    unsigned short* __restrict__ kout,      // [16384, 64]
    unsigned short* __restrict__ vt)        // [4][64][4096]
{
    __shared__ unsigned short Wl[2][12288];     // 49152 B, per-chunk image
    __shared__ unsigned short Xl[2][32][72];    //  9216 B (reused as Vsh[64][40])

    const int tid  = threadIdx.x;
    const int wave = tid >> 6;
    const int lane = tid & 63;
    const int l16  = lane & 15;
    const int quad = lane >> 4;
    const int row0 = blockIdx.x * 32;
    const int mq   = wave & 1;           // M-quarter (16 rows)
    const int ng   = wave >> 1;          // N-group: tiles ng*3 .. ng*3+2

    const bool xst = tid < 256;
    const int xrow = tid >> 3;           // x row (tid<256)
    const int xc8  = (tid & 7) * 8;

    f32x4 acc[3];
#pragma unroll
    for (int j = 0; j < 3; ++j) acc[j] = (f32x4){0.f, 0.f, 0.f, 0.f};

    // ---- stage chunk 0 into buffer 0 ----
#pragma unroll
    for (int m = 0; m < 3; ++m)
        GLD_LDS16(wt2 + (size_t)(m * 4096 + wave * 512 + lane * 8),
                  &Wl[0][m * 4096 + wave * 512]);
    if (xst) {
        const float* xs = x + (size_t)(row0 + xrow) * C_EMB + xc8;
        float4 a = *(const float4*)(xs);
        float4 b = *(const float4*)(xs + 4);
        int4 ai = make_int4((int)pk2bf(a.x, a.y), (int)pk2bf(a.z, a.w),
                            (int)pk2bf(b.x, b.y), (int)pk2bf(b.z, b.w));
        *(short8*)&Xl[0][xrow][xc8] = *(short8*)&ai;
    }
    __syncthreads();

    for (int c = 0; c < 8; ++c) {
        const int bb = c & 1;
        if (c < 7) {                     // stage chunk c+1 into other buffer
            const int nb = bb ^ 1;
            const size_t g0 = (size_t)(c + 1) * 12288;
#pragma unroll
            for (int m = 0; m < 3; ++m)
                GLD_LDS16(wt2 + g0 + (size_t)(m * 4096 + wave * 512 + lane * 8),
                          &Wl[nb][m * 4096 + wave * 512]);
            if (xst) {
                const float* xs = x + (size_t)(row0 + xrow) * C_EMB + (c + 1) * 64 + xc8;
                float4 a = *(const float4*)(xs);
                float4 b = *(const float4*)(xs + 4);
                int4 ai = make_int4((int)pk2bf(a.x, a.y), (int)pk2bf(a.z, a.w),
                                    (int)pk2bf(b.x, b.y), (int)pk2bf(b.z, b.w));
                *(short8*)&Xl[nb][xrow][xc8] = *(short8*)&ai;
            }
        }

        // compute on buffer bb: 2 kc x (1 A-frag, 3 B-frags, 3 MFMA)
#pragma unroll
        for (int kc = 0; kc < 2; ++kc) {
            short8 a0 = *(const short8*)&Xl[bb][mq * 16 + l16][kc * 32 + quad * 8];
#pragma unroll
            for (int j = 0; j < 3; ++j) {
                const int ct = ng * 3 + j;
                short8 bfr = *(const short8*)&Wl[bb][(ct * 128 + kc * 64 + lane) * 8];
                acc[j] = __builtin_amdgcn_mfma_f32_16x16x32_bf16(a0, bfr, acc[j], 0, 0, 0);
            }
        }
        __syncthreads();
    }

    // epilogue: wave owns (mq, tiles ng*3..ng*3+2); tile ct: m=ct>>2, n=ct&3
    unsigned short (*Vsh)[40] = (unsigned short (*)[40]) & Xl[0][0][0];  // 5120 B
#pragma unroll
    for (int j = 0; j < 3; ++j) {
        const int ct = ng * 3 + j;
        const int m  = ct >> 2;
        const int n  = ct & 3;
#pragma unroll
        for (int r = 0; r < 4; ++r) {
            const int row = row0 + mq * 16 + quad * 4 + r;
            if (m == 0)
                qout[(size_t)row * HEAD + n * 16 + l16] = f2bf(acc[j][r] * C2);
            else if (m == 1)
                kout[(size_t)row * HEAD + n * 16 + l16] = f2bf(acc[j][r]);
            else
                Vsh[n * 16 + l16][mq * 16 + quad * 4 + r] = f2bf(acc[j][r]);
        }
    }
    __syncthreads();
    if (tid < 256) {
        int h  = tid >> 2;
        int tc = (tid & 3) * 8;
        int b  = row0 >> 12;
        int t0 = row0 & (T_SEQ - 1);
        unsigned short* dst = vt + ((size_t)(b * HEAD + h)) * T_SEQ + t0 + tc;
        *(short8*)dst = *(const short8*)&Vsh[h][tc];
    }
}

// stage one V row-chunk (16 cols from sc) phi-swizzled:
// col c bits [s|d|q1 q0|r1 r0] -> position [s|q1 q0|d|r1 r0]
__device__ __forceinline__ void stage_v(unsigned short (*Vbuf)[72], int sr, int phiA,
                                        short8 v0, short8 v1) {
    *(short4v*)&Vbuf[sr][phiA]      = __builtin_shufflevector(v0, v0, 0, 1, 2, 3);
    *(short4v*)&Vbuf[sr][phiA + 8]  = __builtin_shufflevector(v0, v0, 4, 5, 6, 7);
    *(short4v*)&Vbuf[sr][phiA + 16] = __builtin_shufflevector(v1, v1, 0, 1, 2, 3);
    *(short4v*)&Vbuf[sr][phiA + 24] = __builtin_shufflevector(v1, v1, 4, 5, 6, 7);
}

// ---------------- Attention phase 1: dual q-group per wave -------------------
// 4 waves x 32 q-rows = 128 q-rows/block, 256 thr. Each K/V LDS fragment read
// (ds_read_b128) feeds TWO MFMAs (q-groups) -> LDS read bytes per q-row -44%
// vs the 8-wave/16-row version. Same job map (EPB 144, CHUNK 8, LPT).
__global__ __launch_bounds__(256) void attn1_kernel(
    const unsigned short* __restrict__ qb,  // [B*T, 64] pre-scaled
    const unsigned short* __restrict__ kb,  // [B*T, 64]
    const unsigned short* __restrict__ vt,  // [4][64][4096]
    unsigned short* __restrict__ po,        // [576][128][64] bf16 partials
    float* __restrict__ pl)                 // [576][128]
{
    __shared__ unsigned short Ks[2][64][72];    // [buf][kpos][h]
    __shared__ unsigned short Vs[2][64][72];    // [buf][h][phi(kpos)]

    const int tid  = threadIdx.x;
    const int wave = tid >> 6;            // 0..3
    const int lane = tid & 63;
    const int l16  = lane & 15;
    const int quad = lane >> 4;

    const int b = blockIdx.x / EPB;
    const int e = (EPB - 1) - (blockIdx.x % EPB);   // LPT: big-np blocks first
    // decode e -> (Q, c): group g has Q in [4g,4g+4), nc=g+1, base 2g(g+1)
    int g = 0;
#pragma unroll
    for (int gg = 1; gg < 8; ++gg) if (e >= 2 * gg * (gg + 1)) g = gg;
    const int rem = e - 2 * g * (g + 1);
    const int t   = rem / (g + 1);
    const int c   = rem - t * (g + 1);
    const int Q   = 4 * g + t;            // q-tile of 128 rows, 0..31

    const size_t base = (size_t)b * T_SEQ;
    const int qrow0 = Q * 128 + wave * 32;      // wave's first q-row (owns 32)
    short8 aq[2][2];
#pragma unroll
    for (int qg = 0; qg < 2; ++qg) {
        const int qr = qrow0 + qg * 16 + l16;
        aq[qg][0] = *(const short8*)(qb + (base + qr) * HEAD + quad * 8);
        aq[qg][1] = *(const short8*)(qb + (base + qr) * HEAD + 32 + quad * 8);
    }

    float lacc[2] = {0.f, 0.f};
    f32x4 o[2][4];
#pragma unroll
    for (int qg = 0; qg < 2; ++qg)
#pragma unroll
        for (int n = 0; n < 4; ++n) o[qg][n] = (f32x4){0.f, 0.f, 0.f, 0.f};

    const int nk  = 2 * Q + 2;                  // causal k-tiles for this q-tile
    const int kt0 = c * CHUNK;
    const int np  = min(CHUNK, nk - kt0);       // 2..8 64-wide iterations

    // staging role: 256 threads, each 32 B of K and 32 B of V per tile
    const int sr   = tid >> 2;            // 0..63 (K k-row / V h-row)
    const int sc   = (tid & 3) * 16;      // 0,16,32,48
    const int phiA = (sc & 32) + ((sc & 16) >> 2);

    short8 kra, krb, vra, vrb;
    {
        const int kbase = kt0 * 64;
        const unsigned short* ksrc = kb + (base + kbase + sr) * HEAD + sc;
        const unsigned short* vsrc = vt + ((size_t)(b * HEAD + sr)) * T_SEQ + kbase + sc;
        kra = *(const short8*)(ksrc);     krb = *(const short8*)(ksrc + 8);
        vra = *(const short8*)(vsrc);     vrb = *(const short8*)(vsrc + 8);
    }
    *(short8*)&Ks[0][sr][sc]     = kra;  *(short8*)&Ks[0][sr][sc + 8] = krb;
    stage_v(Vs[0], sr, phiA, vra, vrb);

    for (int p = 0; p < np; ++p) {
        const int cur = p & 1;
        const int kbase = (kt0 + p) * 64;
        __syncthreads();                 // LDS[cur] ready; prev-iter reads done

        if (p + 1 < np) {                // prefetch next tile into regs
            const int nb = kbase + 64;
            const unsigned short* ksrc = kb + (base + nb + sr) * HEAD + sc;
            const unsigned short* vsrc = vt + ((size_t)(b * HEAD + sr)) * T_SEQ + nb + sc;
            kra = *(const short8*)(ksrc);  krb = *(const short8*)(ksrc + 8);
            vra = *(const short8*)(vsrc);  vrb = *(const short8*)(vsrc + 8);
        }

        // wave-level early-out: tile fully beyond this wave's causal range
        const bool live = (kbase <= qrow0 + 31);
        if (live) {
            // S^T = K.Q^T: lane q=l16 (per group), k = kbase + n*16 + quad*4 + r
            f32x4 s[2][4];
            __builtin_amdgcn_s_setprio(1);   // T5: favor MFMA waves
#pragma unroll
            for (int n = 0; n < 4; ++n) {
                short8 bk0 = *(const short8*)&Ks[cur][n * 16 + l16][quad * 8];
                short8 bk1 = *(const short8*)&Ks[cur][n * 16 + l16][32 + quad * 8];
#pragma unroll
                for (int qg = 0; qg < 2; ++qg) {      // frag reuse: 2 MFMAs/read
                    f32x4 accS = (f32x4){0.f, 0.f, 0.f, 0.f};
                    accS = __builtin_amdgcn_mfma_f32_16x16x32_bf16(bk0, aq[qg][0], accS, 0, 0, 0);
                    accS = __builtin_amdgcn_mfma_f32_16x16x32_bf16(bk1, aq[qg][1], accS, 0, 0, 0);
                    s[qg][n] = accS;
                }
            }
            __builtin_amdgcn_s_setprio(0);

            // P = exp2(S); zero masked cols on diagonal tiles
#pragma unroll
            for (int qg = 0; qg < 2; ++qg)
#pragma unroll
                for (int n = 0; n < 4; ++n)
#pragma unroll
                    for (int r = 0; r < 4; ++r)
                        s[qg][n][r] = __builtin_amdgcn_exp2f(s[qg][n][r]);

            if (kbase + 63 > qrow0) {
                const int cb = kbase + quad * 4;
#pragma unroll
                for (int qg = 0; qg < 2; ++qg) {
                    const int qr = qrow0 + qg * 16 + l16;
#pragma unroll
                    for (int n = 0; n < 4; ++n)
#pragma unroll
                        for (int r = 0; r < 4; ++r)
                            if (cb + n * 16 + r > qr) s[qg][n][r] = 0.f;
                }
            }

#pragma unroll
            for (int qg = 0; qg < 2; ++qg)
#pragma unroll
                for (int n = 0; n < 4; ++n)
                    lacc[qg] += (s[qg][n][0] + s[qg][n][1]) + (s[qg][n][2] + s[qg][n][3]);

            // pack P per group (k-order matches phi-swizzled V)
            short8 pa[2][2];
#pragma unroll
            for (int qg = 0; qg < 2; ++qg)
#pragma unroll
                for (int st = 0; st < 2; ++st) {
                    int4 ai = make_int4(
                        (int)pk2bf(s[qg][2 * st][0],     s[qg][2 * st][1]),
                        (int)pk2bf(s[qg][2 * st][2],     s[qg][2 * st][3]),
                        (int)pk2bf(s[qg][2 * st + 1][0], s[qg][2 * st + 1][1]),
                        (int)pk2bf(s[qg][2 * st + 1][2], s[qg][2 * st + 1][3]));
                    pa[qg][st] = *(short8*)&ai;
                }

            // PV: each V fragment read feeds both q-groups
            __builtin_amdgcn_s_setprio(1);
#pragma unroll
            for (int st = 0; st < 2; ++st)
#pragma unroll
                for (int n = 0; n < 4; ++n) {
                    short8 bv = *(const short8*)&Vs[cur][n * 16 + l16][32 * st + quad * 8];
                    o[0][n] = __builtin_amdgcn_mfma_f32_16x16x32_bf16(pa[0][st], bv, o[0][n], 0, 0, 0);
                    o[1][n] = __builtin_amdgcn_mfma_f32_16x16x32_bf16(pa[1][st], bv, o[1][n], 0, 0, 0);
                }
            __builtin_amdgcn_s_setprio(0);
        }

        if (p + 1 < np) {                // stage next tile into the other buffer
            const int nxt = cur ^ 1;
            *(short8*)&Ks[nxt][sr][sc]     = kra;  *(short8*)&Ks[nxt][sr][sc + 8] = krb;
            stage_v(Vs[nxt], sr, phiA, vra, vrb);
        }
    }

    // reduce l over the quad dimension (q-row = l16 per lane, per group)
#pragma unroll
    for (int qg = 0; qg < 2; ++qg) {
        lacc[qg] += __shfl_xor(lacc[qg], 16);
        lacc[qg] += __shfl_xor(lacc[qg], 32);
    }

    const int pid = blockIdx.x;
#pragma unroll
    for (int qg = 0; qg < 2; ++qg) {
#pragma unroll
        for (int n = 0; n < 4; ++n)
#pragma unroll
            for (int r = 0; r < 4; ++r) {
                int lr = wave * 32 + qg * 16 + quad * 4 + r;    // 0..127
                po[(size_t)pid * 8192 + lr * 64 + n * 16 + l16] = f2bf(o[qg][n][r]);
            }
        if (quad == 0)
            pl[pid * 128 + wave * 32 + qg * 16 + l16] = lacc[qg];
    }
}

// ---------------- Combine: sum <=8 bf16 partials, normalize ----------------
// pid mapping matches attn1's LPT-reversed e decode: pid(b,e) = b*EPB+(EPB-1-e)
__global__ __launch_bounds__(256) void combine_kernel(
    const unsigned short* __restrict__ po, const float* __restrict__ pl,
    float* __restrict__ out)
{
    const int gth = blockIdx.x * 256 + threadIdx.x;   // octet index, 131072 total
    const int h8  = gth & 7;
    const int row = gth >> 3;
    const int lr  = row & 127;
    const int Q   = (row >> 7) & 31;
    const int b   = row >> 12;
    const int g   = Q >> 2;
    const int rem = Q & 3;
    const int nc  = g + 1;
    const int e0  = 2 * g * (g + 1) + rem * (g + 1);
    const int pid0 = b * EPB + (EPB - 1 - e0);        // chunk cc lives at pid0-cc

    float l = 0.f;
    float acc[8];
#pragma unroll
    for (int i = 0; i < 8; ++i) acc[i] = 0.f;
    for (int cc = 0; cc < nc; ++cc) {
        l += pl[(pid0 - cc) * 128 + lr];
        short8 p8 = *(const short8*)(po + (size_t)(pid0 - cc) * 8192 + lr * 64 + h8 * 8);
#pragma unroll
        for (int i = 0; i < 8; ++i) acc[i] += bf2f((unsigned short)p8[i]);
    }
    float inv = 1.f / l;
    float4 r0 = make_float4(acc[0] * inv, acc[1] * inv, acc[2] * inv, acc[3] * inv);
    float4 r1 = make_float4(acc[4] * inv, acc[5] * inv, acc[6] * inv, acc[7] * inv);
    float* dst = out + (size_t)gth * 8;
    *(float4*)dst       = r0;
    *(float4*)(dst + 4) = r1;
}

extern "C" void kernel_launch(void* const* d_in, const int* in_sizes, int n_in,
                              void* d_out, int out_size, void* d_ws, size_t ws_size,
                              hipStream_t stream) {
    const float* x  = (const float*)d_in[0];
    const float* Wq = (const float*)d_in[1];
    const float* Wk = (const float*)d_in[2];
    const float* Wv = (const float*)d_in[3];
    float* out = (float*)d_out;

    char* ws = (char*)d_ws;
    unsigned short* qb = (unsigned short*)(ws);                 // 2 MB
    unsigned short* kb = (unsigned short*)(ws + (2u << 20));    // 2 MB
    unsigned short* vt = (unsigned short*)(ws + (4u << 20));    // 2 MB
    unsigned short* wt2 = (unsigned short*)(ws + (6u << 20));   // 192 KB
    float* pl = (float*)(ws + (6u << 20) + 196608);             // 294912 B
    unsigned short* po = (unsigned short*)(ws + (6u << 20) + 196608 + 294912); // 9.4 MB

    wcvt_kernel<<<dim3(192), dim3(64), 0, stream>>>(Wq, Wk, Wv, wt2);
    proj_kernel<<<dim3(512), dim3(512), 0, stream>>>(x, wt2, qb, kb, vt);
    attn1_kernel<<<dim3(NBATCH * EPB), dim3(256), 0, stream>>>(qb, kb, vt, po, pl);
    combine_kernel<<<dim3(512), dim3(256), 0, stream>>>(po, pl, out);
}